// Round 2
// baseline (8122.917 us; speedup 1.0000x reference)
//
#include <hip/hip_runtime.h>
#include <math.h>

#define HDIM 256
#define IDIM 128
#define ODIM 128
#define DTc 0.03f
#define ALPHAc 0.9f
#define NWG 128

// ---------------------------------------------------------------------------
// Grid barrier for a co-resident persistent kernel (128 WGs <= 256 CUs).
// Two-level arrive (8 spread sub-counters -> root) + release word, all
// agent-scope atomics. Release fence (L2 writeback) before arrive, acquire
// fence (L2 invalidate) after release observed -> plain x loads/stores are
// cross-XCD correct.
// bar layout (ints): sub[i] at bar[i*32] (128B apart), root at bar[256],
// rel at bar[288]. Must be zeroed before kernel start.
// ---------------------------------------------------------------------------
__device__ __forceinline__ void grid_barrier(int* bar, int gen) {
    __syncthreads();
    __builtin_amdgcn_fence(__ATOMIC_RELEASE, "agent");   // wb dirty L2 (our x writes)
    if (threadIdx.x == 0) {
        int* sub  = bar + ((blockIdx.x & 7) << 5);
        int* root = bar + 256;
        int* rel  = bar + 288;
        int c = __hip_atomic_fetch_add(sub, 1, __ATOMIC_RELAXED, __HIP_MEMORY_SCOPE_AGENT);
        if (c == 15) {
            int r = __hip_atomic_fetch_add(root, 1, __ATOMIC_RELAXED, __HIP_MEMORY_SCOPE_AGENT);
            if (r == 7) {
                // all 128 arrived; reset counters, then publish gen
                #pragma unroll
                for (int i = 0; i < 8; ++i)
                    __hip_atomic_store(bar + (i << 5), 0, __ATOMIC_RELAXED, __HIP_MEMORY_SCOPE_AGENT);
                __hip_atomic_store(root, 0, __ATOMIC_RELAXED, __HIP_MEMORY_SCOPE_AGENT);
                __hip_atomic_store(rel, gen, __ATOMIC_RELEASE, __HIP_MEMORY_SCOPE_AGENT);
            } else {
                while (__hip_atomic_load(rel, __ATOMIC_RELAXED, __HIP_MEMORY_SCOPE_AGENT) < gen) { }
            }
        } else {
            while (__hip_atomic_load(rel, __ATOMIC_RELAXED, __HIP_MEMORY_SCOPE_AGENT) < gen) { }
        }
    }
    __syncthreads();
    __builtin_amdgcn_fence(__ATOMIC_ACQUIRE, "agent");   // inv L1/L2 -> fresh x reads
}

// ---------------------------------------------------------------------------
// Persistent fused kernel. WG (bx): bi = bx>>4 (i-tile of 32 rows),
// bj = bx&15 (j-tile of 16 cols). Thread t: ti=t>>4, tj=t&15 owns elements
// (tile_i+ti, tile_j+tj) and (tile_i+ti+16, tile_j+tj).
// V rows for the i-tile live in LDS per layer; z and own-x live in registers.
// x state ping-pongs buf0/buf1 through global memory each step.
// ---------------------------------------------------------------------------
__global__ __launch_bounds__(256) void unicornn_fused(
    const float* __restrict__ x_in,   // [256,128]
    const float* __restrict__ w_in,   // [256,128]
    const float* __restrict__ b_in,   // [256]
    const float* __restrict__ w_rec,  // [2,256]
    const float* __restrict__ v_rec,  // [2,256,256]
    const float* __restrict__ b_rec,  // [2,256]
    const float* __restrict__ w_out,  // [128,256]
    const float* __restrict__ b_out,  // [128]
    float* __restrict__ out,          // [256,128]
    float* __restrict__ buf0, float* __restrict__ buf1,
    int* __restrict__ bar)
{
    __shared__ float Vs[32][260];   // V rows of i-tile (per layer); reused as h-stage at end
    __shared__ float Xs[16][260];   // x rows of j-tile (per step); reused for w_in/w_out

    const int t  = threadIdx.x;
    const int bx = blockIdx.x;
    const int bi = bx >> 4, bj = bx & 15;
    const int tile_i = bi << 5, tile_j = bj << 4;
    const int ti = t >> 4, tj = t & 15;
    const int gi0 = tile_i + ti, gi1 = gi0 + 16;
    const int gj  = tile_j + tj;
    int gen = 1;

    // ================= phase 0: h = x_in @ w_in^T + b_in (own tile) =========
    {
        const float4* Ag = (const float4*)(x_in + tile_i * IDIM);   // 32 rows x 32 q
        for (int idx = t; idx < 1024; idx += 256) {
            int row = idx >> 5, q = idx & 31;
            *(float4*)&Vs[row][q << 2] = Ag[idx];
        }
        const float4* Bg = (const float4*)(w_in + tile_j * IDIM);   // 16 rows x 32 q
        for (int idx = t; idx < 512; idx += 256) {
            int row = idx >> 5, q = idx & 31;
            *(float4*)&Xs[row][q << 2] = Bg[idx];
        }
    }
    __syncthreads();

    float xv0, xv1;
    {
        float a0 = 0.f, a1 = 0.f;
        #pragma unroll 8
        for (int kq = 0; kq < 32; ++kq) {
            float4 wb = *(const float4*)&Xs[tj][kq << 2];
            float4 r0 = *(const float4*)&Vs[ti][kq << 2];
            float4 r1 = *(const float4*)&Vs[ti + 16][kq << 2];
            a0 = fmaf(r0.x, wb.x, a0); a0 = fmaf(r0.y, wb.y, a0);
            a0 = fmaf(r0.z, wb.z, a0); a0 = fmaf(r0.w, wb.w, a0);
            a1 = fmaf(r1.x, wb.x, a1); a1 = fmaf(r1.y, wb.y, a1);
            a1 = fmaf(r1.z, wb.z, a1); a1 = fmaf(r1.w, wb.w, a1);
        }
        float bj_in = b_in[gj];
        xv0 = a0 + bj_in;
        xv1 = a1 + bj_in;
    }
    float* cur = buf0;
    float* nxt = buf1;
    cur[gi0 * HDIM + gj] = xv0;
    cur[gi1 * HDIM + gj] = xv1;
    grid_barrier(bar, gen++);

    // ================= recurrent layers ======================================
    for (int l = 0; l < 2; ++l) {
        // load this layer's V rows [tile_i, tile_i+32) into LDS (kept all layer)
        {
            const float4* Vg = (const float4*)(v_rec + l * HDIM * HDIM + tile_i * HDIM);
            for (int idx = t; idx < 2048; idx += 256) {   // 32 rows x 64 q
                int row = idx >> 6, q = idx & 63;
                *(float4*)&Vs[row][q << 2] = Vg[idx];
            }
        }
        const float Wj  = w_rec[l * HDIM + gj];
        const float bjr = b_rec[l * HDIM + gj];
        float zv0 = 0.f, zv1 = 0.f;

        for (int s = 0; s < HDIM; ++s) {
            // stage x rows [tile_j, tile_j+16) x 256 into Xs
            const float4* Xg = (const float4*)(cur + tile_j * HDIM);
            #pragma unroll
            for (int r = 0; r < 4; ++r) {
                int idx = t + (r << 8);
                int row = idx >> 6, q = idx & 63;
                *(float4*)&Xs[row][q << 2] = Xg[idx];
            }
            __syncthreads();

            float acc0 = 0.f, acc1 = 0.f;
            #pragma unroll 8
            for (int kq = 0; kq < 64; ++kq) {
                float4 xb = *(const float4*)&Xs[tj][kq << 2];
                float4 v0 = *(const float4*)&Vs[ti][kq << 2];
                float4 v1 = *(const float4*)&Vs[ti + 16][kq << 2];
                acc0 = fmaf(v0.x, xb.x, acc0); acc0 = fmaf(v0.y, xb.y, acc0);
                acc0 = fmaf(v0.z, xb.z, acc0); acc0 = fmaf(v0.w, xb.w, acc0);
                acc1 = fmaf(v1.x, xb.x, acc1); acc1 = fmaf(v1.y, xb.y, acc1);
                acc1 = fmaf(v1.z, xb.z, acc1); acc1 = fmaf(v1.w, xb.w, acc1);
            }

            float pre0 = fmaf(Wj, xv0, acc0) + bjr;
            float pre1 = fmaf(Wj, xv1, acc1) + bjr;
            zv0 -= DTc * (tanhf(pre0) + ALPHAc * xv0);
            zv1 -= DTc * (tanhf(pre1) + ALPHAc * xv1);
            xv0 = fmaf(DTc, zv0, xv0);
            xv1 = fmaf(DTc, zv1, xv1);
            nxt[gi0 * HDIM + gj] = xv0;
            nxt[gi1 * HDIM + gj] = xv1;

            grid_barrier(bar, gen++);
            float* tmp = cur; cur = nxt; nxt = tmp;
        }
    }

    // ================= output layer: out = h @ w_out^T + b_out ==============
    // WG computes out[tile_i..+32][bj*8..+8]; h rows from cur (published).
    {
        const float4* Hg = (const float4*)(cur + tile_i * HDIM);    // 32 rows x 64 q
        for (int idx = t; idx < 2048; idx += 256) {
            int row = idx >> 6, q = idx & 63;
            *(float4*)&Vs[row][q << 2] = Hg[idx];
        }
        const float4* Wg = (const float4*)(w_out + (bj << 3) * HDIM); // 8 rows x 64 q
        for (int idx = t; idx < 512; idx += 256) {
            int row = idx >> 6, q = idx & 63;
            *(float4*)&Xs[row][q << 2] = Wg[idx];
        }
    }
    __syncthreads();
    {
        const int il = t >> 3, jo = t & 7;
        float acc = 0.f;
        #pragma unroll 8
        for (int kq = 0; kq < 64; ++kq) {
            float4 a = *(const float4*)&Vs[il][kq << 2];
            float4 b = *(const float4*)&Xs[jo][kq << 2];
            acc = fmaf(a.x, b.x, acc); acc = fmaf(a.y, b.y, acc);
            acc = fmaf(a.z, b.z, acc); acc = fmaf(a.w, b.w, acc);
        }
        int go = (bj << 3) + jo;
        out[(tile_i + il) * ODIM + go] = acc + b_out[go];
    }
}

extern "C" void kernel_launch(void* const* d_in, const int* in_sizes, int n_in,
                              void* d_out, int out_size, void* d_ws, size_t ws_size,
                              hipStream_t stream) {
    const float* x     = (const float*)d_in[0];
    const float* w_in  = (const float*)d_in[1];
    const float* b_in  = (const float*)d_in[2];
    const float* w_rec = (const float*)d_in[3];
    const float* v_rec = (const float*)d_in[4];
    const float* b_rec = (const float*)d_in[5];
    const float* w_out = (const float*)d_in[6];
    const float* b_out = (const float*)d_in[7];
    float* out = (float*)d_out;

    float* buf0 = (float*)d_ws;
    float* buf1 = buf0 + HDIM * HDIM;
    int*   bar  = (int*)(buf1 + HDIM * HDIM);

    // barrier state must start zeroed (ws is re-poisoned 0xAA before each call)
    hipMemsetAsync(bar, 0, 2048, stream);

    unicornn_fused<<<NWG, 256, 0, stream>>>(
        x, w_in, b_in, w_rec, v_rec, b_rec, w_out, b_out,
        out, buf0, buf1, bar);
}

// Round 5
// 3564.993 us; speedup vs baseline: 2.2785x; 2.2785x over previous
//
#include <hip/hip_runtime.h>
#include <math.h>

#define HDIM 256
#define IDIM 128
#define ODIM 128
#define DTc 0.03f
#define ALPHAc 0.9f
#define NWG 128

typedef float f32x4 __attribute__((ext_vector_type(4)));

// ---------------------------------------------------------------------------
// Cross-XCD coherent data path WITHOUT cache-maintenance ops:
//   stores: write-through to L3 (sc0 sc1) + vmcnt(0) completion in-block
//   loads : bypass L1/L2, read at L3 (sc0 sc1), batched 4x dwordx4 + one wait
// L3 (Infinity Cache) is the cross-XCD coherence point; all cross-WG traffic
// uses it directly, so no buffer_wbl2 / buffer_inv is ever needed.
// ---------------------------------------------------------------------------
__device__ __forceinline__ void store2_wt(float* p0, float v0, float* p1, float v1) {
    asm volatile(
        "global_store_dword %0, %2, off sc0 sc1\n\t"
        "global_store_dword %1, %3, off sc0 sc1\n\t"
        "s_waitcnt vmcnt(0)"
        :: "v"(p0), "v"(p1), "v"(v0), "v"(v1) : "memory");
}

__device__ __forceinline__ void load4_x4_sc(const f32x4* p0, const f32x4* p1,
                                            const f32x4* p2, const f32x4* p3,
                                            f32x4& r0, f32x4& r1, f32x4& r2, f32x4& r3) {
    asm volatile(
        "global_load_dwordx4 %0, %4, off sc0 sc1\n\t"
        "global_load_dwordx4 %1, %5, off sc0 sc1\n\t"
        "global_load_dwordx4 %2, %6, off sc0 sc1\n\t"
        "global_load_dwordx4 %3, %7, off sc0 sc1\n\t"
        "s_waitcnt vmcnt(0)"
        : "=&v"(r0), "=&v"(r1), "=&v"(r2), "=&v"(r3)
        : "v"(p0), "v"(p1), "v"(p2), "v"(p3)
        : "memory");
}

// ---------------------------------------------------------------------------
// Step-indexed grid barrier: slot s uses bar[s*288 ..]. 8 sub-counters on
// separate 128B lines (16 arrivals each, indexed bx&7) -> root line (==8).
// Relaxed agent-scope atomics only; counters never reset (fresh slot/step).
// Caller guarantees its wt-stores completed (vmcnt0) and WG is synced.
// ---------------------------------------------------------------------------
__device__ __forceinline__ void flat_barrier(int* bar, int slot, int bx) {
    if (threadIdx.x == 0) {
        int* base = bar + slot * 288;
        int* sub  = base + ((bx & 7) << 5);
        int* root = base + 256;
        int c = __hip_atomic_fetch_add(sub, 1, __ATOMIC_RELAXED, __HIP_MEMORY_SCOPE_AGENT);
        if (c == 15)
            __hip_atomic_fetch_add(root, 1, __ATOMIC_RELAXED, __HIP_MEMORY_SCOPE_AGENT);
        while (__hip_atomic_load(root, __ATOMIC_RELAXED, __HIP_MEMORY_SCOPE_AGENT) < 8) { }
    }
    __syncthreads();
}

// ---------------------------------------------------------------------------
// Persistent fused kernel. WG bx: bi=bx>>4 (32-row i-tile), bj=bx&15 (16-col
// j-tile). Thread t: ti=t>>4, tj=t&15 owns (tile_i+ti, gj) and (+16, gj).
// V rows in LDS per layer; z and own-x in registers; x state ping-pongs
// buf0/buf1 through L3 each step.
// ---------------------------------------------------------------------------
__global__ __launch_bounds__(256) void unicornn_fused(
    const float* __restrict__ x_in,   // [256,128]
    const float* __restrict__ w_in,   // [256,128]
    const float* __restrict__ b_in,   // [256]
    const float* __restrict__ w_rec,  // [2,256]
    const float* __restrict__ v_rec,  // [2,256,256]
    const float* __restrict__ b_rec,  // [2,256]
    const float* __restrict__ w_out,  // [128,256]
    const float* __restrict__ b_out,  // [128]
    float* __restrict__ out,          // [256,128]
    float* __restrict__ buf0, float* __restrict__ buf1,
    int* __restrict__ bar)
{
    __shared__ float Vs[32][260];   // V rows of i-tile (per layer); h-stage at end
    __shared__ float Xs[16][260];   // x rows of j-tile (per step); w_in stage

    const int t  = threadIdx.x;
    const int bx = blockIdx.x;
    const int tile_i = (bx >> 4) << 5, tile_j = (bx & 15) << 4;
    const int ti = t >> 4, tj = t & 15;
    const int gi0 = tile_i + ti, gi1 = gi0 + 16;
    const int gj  = tile_j + tj;
    int slot = 0;

    // ================= phase 0: h = x_in @ w_in^T + b_in (own tile) =========
    {
        const float4* Ag = (const float4*)(x_in + tile_i * IDIM);   // 32 rows x 32 q
        for (int idx = t; idx < 1024; idx += 256) {
            int row = idx >> 5, q = idx & 31;
            *(float4*)&Vs[row][q << 2] = Ag[idx];
        }
        const float4* Bg = (const float4*)(w_in + tile_j * IDIM);   // 16 rows x 32 q
        for (int idx = t; idx < 512; idx += 256) {
            int row = idx >> 5, q = idx & 31;
            *(float4*)&Xs[row][q << 2] = Bg[idx];
        }
    }
    __syncthreads();

    float xv0, xv1;
    {
        float a0 = 0.f, a1 = 0.f;
        #pragma unroll 8
        for (int kq = 0; kq < 32; ++kq) {
            float4 wb = *(const float4*)&Xs[tj][kq << 2];
            float4 r0 = *(const float4*)&Vs[ti][kq << 2];
            float4 r1 = *(const float4*)&Vs[ti + 16][kq << 2];
            a0 = fmaf(r0.x, wb.x, a0); a0 = fmaf(r0.y, wb.y, a0);
            a0 = fmaf(r0.z, wb.z, a0); a0 = fmaf(r0.w, wb.w, a0);
            a1 = fmaf(r1.x, wb.x, a1); a1 = fmaf(r1.y, wb.y, a1);
            a1 = fmaf(r1.z, wb.z, a1); a1 = fmaf(r1.w, wb.w, a1);
        }
        float bj_in = b_in[gj];
        xv0 = a0 + bj_in;
        xv1 = a1 + bj_in;
    }
    float* cur = buf0;
    float* nxt = buf1;
    store2_wt(cur + gi0 * HDIM + gj, xv0, cur + gi1 * HDIM + gj, xv1);
    __syncthreads();
    flat_barrier(bar, slot++, bx);

    // ================= recurrent layers ======================================
    for (int l = 0; l < 2; ++l) {
        {
            const float4* Vg = (const float4*)(v_rec + l * HDIM * HDIM + tile_i * HDIM);
            for (int idx = t; idx < 2048; idx += 256) {   // 32 rows x 64 q
                int row = idx >> 6, q = idx & 63;
                *(float4*)&Vs[row][q << 2] = Vg[idx];
            }
        }
        const float Wj  = w_rec[l * HDIM + gj];
        const float bjr = b_rec[l * HDIM + gj];
        float zv0 = 0.f, zv1 = 0.f;

        for (int s = 0; s < HDIM; ++s) {
            // stage x rows [tile_j, tile_j+16) from L3 (coherent) into Xs
            {
                const f32x4* Xg = (const f32x4*)(cur + tile_j * HDIM);
                f32x4 r0, r1, r2, r3;
                const int i0 = t, i1 = t + 256, i2 = t + 512, i3 = t + 768;
                load4_x4_sc(Xg + i0, Xg + i1, Xg + i2, Xg + i3, r0, r1, r2, r3);
                *(f32x4*)&Xs[i0 >> 6][(i0 & 63) << 2] = r0;
                *(f32x4*)&Xs[i1 >> 6][(i1 & 63) << 2] = r1;
                *(f32x4*)&Xs[i2 >> 6][(i2 & 63) << 2] = r2;
                *(f32x4*)&Xs[i3 >> 6][(i3 & 63) << 2] = r3;
            }
            __syncthreads();

            float acc0 = 0.f, acc1 = 0.f;
            #pragma unroll 8
            for (int kq = 0; kq < 64; ++kq) {
                float4 xb = *(const float4*)&Xs[tj][kq << 2];
                float4 v0 = *(const float4*)&Vs[ti][kq << 2];
                float4 v1 = *(const float4*)&Vs[ti + 16][kq << 2];
                acc0 = fmaf(v0.x, xb.x, acc0); acc0 = fmaf(v0.y, xb.y, acc0);
                acc0 = fmaf(v0.z, xb.z, acc0); acc0 = fmaf(v0.w, xb.w, acc0);
                acc1 = fmaf(v1.x, xb.x, acc1); acc1 = fmaf(v1.y, xb.y, acc1);
                acc1 = fmaf(v1.z, xb.z, acc1); acc1 = fmaf(v1.w, xb.w, acc1);
            }

            float pre0 = fmaf(Wj, xv0, acc0) + bjr;
            float pre1 = fmaf(Wj, xv1, acc1) + bjr;
            zv0 -= DTc * (tanhf(pre0) + ALPHAc * xv0);
            zv1 -= DTc * (tanhf(pre1) + ALPHAc * xv1);
            xv0 = fmaf(DTc, zv0, xv0);
            xv1 = fmaf(DTc, zv1, xv1);

            store2_wt(nxt + gi0 * HDIM + gj, xv0, nxt + gi1 * HDIM + gj, xv1);
            __syncthreads();               // all lanes' wt-stores complete
            flat_barrier(bar, slot++, bx); // all WGs' stores at L3

            float* tmp = cur; cur = nxt; nxt = tmp;
        }
    }

    // ================= output layer: out = h @ w_out^T + b_out ==============
    {
        const f32x4* Hg = (const f32x4*)(cur + tile_i * HDIM);    // 32 rows x 64 q
        {
            f32x4 r0, r1, r2, r3;
            const int i0 = t, i1 = t + 256, i2 = t + 512, i3 = t + 768;
            load4_x4_sc(Hg + i0, Hg + i1, Hg + i2, Hg + i3, r0, r1, r2, r3);
            *(f32x4*)&Vs[i0 >> 6][(i0 & 63) << 2] = r0;
            *(f32x4*)&Vs[i1 >> 6][(i1 & 63) << 2] = r1;
            *(f32x4*)&Vs[i2 >> 6][(i2 & 63) << 2] = r2;
            *(f32x4*)&Vs[i3 >> 6][(i3 & 63) << 2] = r3;
        }
        {
            f32x4 r0, r1, r2, r3;
            const int i0 = t + 1024, i1 = t + 1280, i2 = t + 1536, i3 = t + 1792;
            load4_x4_sc(Hg + i0, Hg + i1, Hg + i2, Hg + i3, r0, r1, r2, r3);
            *(f32x4*)&Vs[i0 >> 6][(i0 & 63) << 2] = r0;
            *(f32x4*)&Vs[i1 >> 6][(i1 & 63) << 2] = r1;
            *(f32x4*)&Vs[i2 >> 6][(i2 & 63) << 2] = r2;
            *(f32x4*)&Vs[i3 >> 6][(i3 & 63) << 2] = r3;
        }
        const float4* Wg = (const float4*)(w_out + ((bx & 15) << 3) * HDIM); // 8 rows x 64 q
        for (int idx = t; idx < 512; idx += 256) {
            int row = idx >> 6, q = idx & 63;
            *(float4*)&Xs[row][q << 2] = Wg[idx];
        }
    }
    __syncthreads();
    {
        const int il = t >> 3, jo = t & 7;
        float acc = 0.f;
        #pragma unroll 8
        for (int kq = 0; kq < 64; ++kq) {
            float4 a = *(const float4*)&Vs[il][kq << 2];
            float4 b = *(const float4*)&Xs[jo][kq << 2];
            acc = fmaf(a.x, b.x, acc); acc = fmaf(a.y, b.y, acc);
            acc = fmaf(a.z, b.z, acc); acc = fmaf(a.w, b.w, acc);
        }
        int go = ((bx & 15) << 3) + jo;
        out[(tile_i + il) * ODIM + go] = acc + b_out[go];
    }
}

extern "C" void kernel_launch(void* const* d_in, const int* in_sizes, int n_in,
                              void* d_out, int out_size, void* d_ws, size_t ws_size,
                              hipStream_t stream) {
    const float* x     = (const float*)d_in[0];
    const float* w_in  = (const float*)d_in[1];
    const float* b_in  = (const float*)d_in[2];
    const float* w_rec = (const float*)d_in[3];
    const float* v_rec = (const float*)d_in[4];
    const float* b_rec = (const float*)d_in[5];
    const float* w_out = (const float*)d_in[6];
    const float* b_out = (const float*)d_in[7];
    float* out = (float*)d_out;

    float* buf0 = (float*)d_ws;
    float* buf1 = buf0 + HDIM * HDIM;
    int*   bar  = (int*)(buf1 + HDIM * HDIM);

    // 513 barrier slots x 288 ints, must start zeroed (ws re-poisoned 0xAA)
    hipMemsetAsync(bar, 0, 513 * 288 * sizeof(int), stream);

    unicornn_fused<<<NWG, 256, 0, stream>>>(
        x, w_in, b_in, w_rec, v_rec, b_rec, w_out, b_out,
        out, buf0, buf1, bar);
}

// Round 6
// 3065.637 us; speedup vs baseline: 2.6497x; 1.1629x over previous
//
#include <hip/hip_runtime.h>
#include <math.h>

#define HDIM 256
#define IDIM 128
#define ODIM 128
#define DTc 0.03f
#define ALPHAc 0.9f
#define NWG 128
#define STATE (HDIM * HDIM)   // 65536 floats per state buffer

typedef float f32x4 __attribute__((ext_vector_type(4)));

// ---------------------------------------------------------------------------
// Cross-XCD coherent data path WITHOUT cache-maintenance ops:
//   stores: write-through to coherence point (sc0 sc1) + in-block vmcnt(0)
//   loads : bypass L1/L2, read at coherence point (sc0 sc1), batched + 1 wait
// ---------------------------------------------------------------------------
__device__ __forceinline__ void store2_wt(float* p0, float v0, float* p1, float v1) {
    asm volatile(
        "global_store_dword %0, %2, off sc0 sc1\n\t"
        "global_store_dword %1, %3, off sc0 sc1\n\t"
        "s_waitcnt vmcnt(0)"
        :: "v"(p0), "v"(p1), "v"(v0), "v"(v1) : "memory");
}

__device__ __forceinline__ void load4_x4_sc(const f32x4* p0, const f32x4* p1,
                                            const f32x4* p2, const f32x4* p3,
                                            f32x4& r0, f32x4& r1, f32x4& r2, f32x4& r3) {
    asm volatile(
        "global_load_dwordx4 %0, %4, off sc0 sc1\n\t"
        "global_load_dwordx4 %1, %5, off sc0 sc1\n\t"
        "global_load_dwordx4 %2, %6, off sc0 sc1\n\t"
        "global_load_dwordx4 %3, %7, off sc0 sc1\n\t"
        "s_waitcnt vmcnt(0)"
        : "=&v"(r0), "=&v"(r1), "=&v"(r2), "=&v"(r3)
        : "v"(p0), "v"(p1), "v"(p2), "v"(p3)
        : "memory");
}

// ---------------------------------------------------------------------------
// Point-to-point step flags. flags[slot][blk] on its own 128B line; the 16
// producer WGs of 32-row block blk each add 1 (after vmcnt0'd stores +
// __syncthreads). Consumers poll their single needed counter to 16.
// Counters are step-indexed (never reset). Max WG skew = 2 steps (proof in
// commit msg) -> 4-buffer state rotation is WAR-safe.
// ---------------------------------------------------------------------------
__device__ __forceinline__ void arrive(int* flags, int slot, int blk) {
    // pre: this WG's sc-stores for `slot` are vmcnt0-complete on ALL lanes
    //      (store2_wt) and a __syncthreads() has executed since.
    if (threadIdx.x == 0)
        __hip_atomic_fetch_add(flags + ((slot << 3) + blk) * 32, 1,
                               __ATOMIC_RELAXED, __HIP_MEMORY_SCOPE_AGENT);
}

__device__ __forceinline__ void wait_block(int* flags, int slot, int blk) {
    if (threadIdx.x == 0) {
        int* f = flags + ((slot << 3) + blk) * 32;
        while (__hip_atomic_load(f, __ATOMIC_RELAXED, __HIP_MEMORY_SCOPE_AGENT) < 16) { }
    }
    __syncthreads();
}

// ---------------------------------------------------------------------------
// Persistent fused kernel. WG bx: bi=bx>>4 (32-row i-tile), bj=bx&15 (16-col
// j-tile). Thread t: ti=t>>4, tj=t&15 owns (tile_i+ti, gj) and (+16, gj).
// V rows in LDS per layer; z and own-x in registers; x state rotates through
// 4 global buffers; cross-WG sync is per-row-block p2p flags.
// ---------------------------------------------------------------------------
__global__ __launch_bounds__(256) void unicornn_fused(
    const float* __restrict__ x_in,   // [256,128]
    const float* __restrict__ w_in,   // [256,128]
    const float* __restrict__ b_in,   // [256]
    const float* __restrict__ w_rec,  // [2,256]
    const float* __restrict__ v_rec,  // [2,256,256]
    const float* __restrict__ b_rec,  // [2,256]
    const float* __restrict__ w_out,  // [128,256]
    const float* __restrict__ b_out,  // [128]
    float* __restrict__ out,          // [256,128]
    float* __restrict__ bufs,         // 4 * STATE floats
    int* __restrict__ flags)          // 513 * 8 * 32 ints, zeroed
{
    __shared__ float Vs[32][260];   // V rows of i-tile (per layer); h-stage at end
    __shared__ float Xs[16][260];   // x rows of j-tile (per step); w_in stage

    const int t  = threadIdx.x;
    const int bx = blockIdx.x;
    const int bi = bx >> 4, bj = bx & 15;
    const int tile_i = bi << 5, tile_j = bj << 4;
    const int ti = t >> 4, tj = t & 15;
    const int gi0 = tile_i + ti, gi1 = gi0 + 16;
    const int gj  = tile_j + tj;
    const int B   = bj >> 1;        // row-block this WG consumes

    // ================= phase 0: h = x_in @ w_in^T + b_in (own tile) =========
    {
        const float4* Ag = (const float4*)(x_in + tile_i * IDIM);   // 32 rows x 32 q
        for (int idx = t; idx < 1024; idx += 256) {
            int row = idx >> 5, q = idx & 31;
            *(float4*)&Vs[row][q << 2] = Ag[idx];
        }
        const float4* Bg = (const float4*)(w_in + tile_j * IDIM);   // 16 rows x 32 q
        for (int idx = t; idx < 512; idx += 256) {
            int row = idx >> 5, q = idx & 31;
            *(float4*)&Xs[row][q << 2] = Bg[idx];
        }
    }
    __syncthreads();

    float xv0, xv1;
    {
        float a0 = 0.f, a1 = 0.f;
        #pragma unroll 8
        for (int kq = 0; kq < 32; ++kq) {
            float4 wb = *(const float4*)&Xs[tj][kq << 2];
            float4 r0 = *(const float4*)&Vs[ti][kq << 2];
            float4 r1 = *(const float4*)&Vs[ti + 16][kq << 2];
            a0 = fmaf(r0.x, wb.x, a0); a0 = fmaf(r0.y, wb.y, a0);
            a0 = fmaf(r0.z, wb.z, a0); a0 = fmaf(r0.w, wb.w, a0);
            a1 = fmaf(r1.x, wb.x, a1); a1 = fmaf(r1.y, wb.y, a1);
            a1 = fmaf(r1.z, wb.z, a1); a1 = fmaf(r1.w, wb.w, a1);
        }
        float bj_in = b_in[gj];
        xv0 = a0 + bj_in;
        xv1 = a1 + bj_in;
    }
    store2_wt(bufs + gi0 * HDIM + gj, xv0, bufs + gi1 * HDIM + gj, xv1);
    __syncthreads();
    arrive(flags, 0, bi);

    // ================= recurrent layers ======================================
    int step = 1;
    for (int l = 0; l < 2; ++l) {
        // stage this layer's V rows [tile_i, tile_i+32) into Vs
        // (WAR vs previous compute reads of Vs is covered by the post-store
        //  __syncthreads of the previous step; RAW covered by wait_block's sync)
        {
            const float4* Vg = (const float4*)(v_rec + l * HDIM * HDIM + tile_i * HDIM);
            for (int idx = t; idx < 2048; idx += 256) {   // 32 rows x 64 q
                int row = idx >> 6, q = idx & 63;
                *(float4*)&Vs[row][q << 2] = Vg[idx];
            }
        }
        const float Wj  = w_rec[l * HDIM + gj];
        const float bjr = b_rec[l * HDIM + gj];
        float zv0 = 0.f, zv1 = 0.f;

        for (int s = 0; s < HDIM; ++s, ++step) {
            // wait for our row-block of state step-1, then stage 16 rows
            wait_block(flags, step - 1, B);
            {
                const float* src = bufs + ((step - 1) & 3) * STATE;
                const f32x4* Xg = (const f32x4*)(src + tile_j * HDIM);
                f32x4 r0, r1, r2, r3;
                const int i0 = t, i1 = t + 256, i2 = t + 512, i3 = t + 768;
                load4_x4_sc(Xg + i0, Xg + i1, Xg + i2, Xg + i3, r0, r1, r2, r3);
                *(f32x4*)&Xs[i0 >> 6][(i0 & 63) << 2] = r0;
                *(f32x4*)&Xs[i1 >> 6][(i1 & 63) << 2] = r1;
                *(f32x4*)&Xs[i2 >> 6][(i2 & 63) << 2] = r2;
                *(f32x4*)&Xs[i3 >> 6][(i3 & 63) << 2] = r3;
            }
            __syncthreads();

            float acc0 = 0.f, acc1 = 0.f;
            #pragma unroll 8
            for (int kq = 0; kq < 64; ++kq) {
                float4 xb = *(const float4*)&Xs[tj][kq << 2];
                float4 v0 = *(const float4*)&Vs[ti][kq << 2];
                float4 v1 = *(const float4*)&Vs[ti + 16][kq << 2];
                acc0 = fmaf(v0.x, xb.x, acc0); acc0 = fmaf(v0.y, xb.y, acc0);
                acc0 = fmaf(v0.z, xb.z, acc0); acc0 = fmaf(v0.w, xb.w, acc0);
                acc1 = fmaf(v1.x, xb.x, acc1); acc1 = fmaf(v1.y, xb.y, acc1);
                acc1 = fmaf(v1.z, xb.z, acc1); acc1 = fmaf(v1.w, xb.w, acc1);
            }

            float pre0 = fmaf(Wj, xv0, acc0) + bjr;
            float pre1 = fmaf(Wj, xv1, acc1) + bjr;
            zv0 -= DTc * (tanhf(pre0) + ALPHAc * xv0);
            zv1 -= DTc * (tanhf(pre1) + ALPHAc * xv1);
            xv0 = fmaf(DTc, zv0, xv0);
            xv1 = fmaf(DTc, zv1, xv1);

            float* dst = bufs + (step & 3) * STATE;
            store2_wt(dst + gi0 * HDIM + gj, xv0, dst + gi1 * HDIM + gj, xv1);
            __syncthreads();               // all lanes' wt-stores acked
            arrive(flags, step, bi);       // publish our contribution
        }
    }

    // ================= output layer: out = h @ w_out^T + b_out ==============
    // needs rows [tile_i, tile_i+32) of the final state = row-block bi
    wait_block(flags, 512, bi);
    {
        const float* hsrc = bufs + (512 & 3) * STATE;
        const f32x4* Hg = (const f32x4*)(hsrc + tile_i * HDIM);   // 32 rows x 64 q
        {
            f32x4 r0, r1, r2, r3;
            const int i0 = t, i1 = t + 256, i2 = t + 512, i3 = t + 768;
            load4_x4_sc(Hg + i0, Hg + i1, Hg + i2, Hg + i3, r0, r1, r2, r3);
            *(f32x4*)&Vs[i0 >> 6][(i0 & 63) << 2] = r0;
            *(f32x4*)&Vs[i1 >> 6][(i1 & 63) << 2] = r1;
            *(f32x4*)&Vs[i2 >> 6][(i2 & 63) << 2] = r2;
            *(f32x4*)&Vs[i3 >> 6][(i3 & 63) << 2] = r3;
        }
        {
            f32x4 r0, r1, r2, r3;
            const int i0 = t + 1024, i1 = t + 1280, i2 = t + 1536, i3 = t + 1792;
            load4_x4_sc(Hg + i0, Hg + i1, Hg + i2, Hg + i3, r0, r1, r2, r3);
            *(f32x4*)&Vs[i0 >> 6][(i0 & 63) << 2] = r0;
            *(f32x4*)&Vs[i1 >> 6][(i1 & 63) << 2] = r1;
            *(f32x4*)&Vs[i2 >> 6][(i2 & 63) << 2] = r2;
            *(f32x4*)&Vs[i3 >> 6][(i3 & 63) << 2] = r3;
        }
        const float4* Wg = (const float4*)(w_out + (bj << 3) * HDIM); // 8 rows x 64 q
        for (int idx = t; idx < 512; idx += 256) {
            int row = idx >> 6, q = idx & 63;
            *(float4*)&Xs[row][q << 2] = Wg[idx];
        }
    }
    __syncthreads();
    {
        const int il = t >> 3, jo = t & 7;
        float acc = 0.f;
        #pragma unroll 8
        for (int kq = 0; kq < 64; ++kq) {
            float4 a = *(const float4*)&Vs[il][kq << 2];
            float4 b = *(const float4*)&Xs[jo][kq << 2];
            acc = fmaf(a.x, b.x, acc); acc = fmaf(a.y, b.y, acc);
            acc = fmaf(a.z, b.z, acc); acc = fmaf(a.w, b.w, acc);
        }
        int go = (bj << 3) + jo;
        out[(tile_i + il) * ODIM + go] = acc + b_out[go];
    }
}

extern "C" void kernel_launch(void* const* d_in, const int* in_sizes, int n_in,
                              void* d_out, int out_size, void* d_ws, size_t ws_size,
                              hipStream_t stream) {
    const float* x     = (const float*)d_in[0];
    const float* w_in  = (const float*)d_in[1];
    const float* b_in  = (const float*)d_in[2];
    const float* w_rec = (const float*)d_in[3];
    const float* v_rec = (const float*)d_in[4];
    const float* b_rec = (const float*)d_in[5];
    const float* w_out = (const float*)d_in[6];
    const float* b_out = (const float*)d_in[7];
    float* out = (float*)d_out;

    float* bufs = (float*)d_ws;                 // 4 * 256KB state rotation
    int*   flags = (int*)(bufs + 4 * STATE);    // 513 slots * 8 blocks * 32 ints

    // flags must start zeroed (ws is re-poisoned 0xAA before each call)
    hipMemsetAsync(flags, 0, 513 * 8 * 32 * sizeof(int), stream);

    unicornn_fused<<<NWG, 256, 0, stream>>>(
        x, w_in, b_in, w_rec, v_rec, b_rec, w_out, b_out,
        out, bufs, flags);
}